// Round 6
// baseline (18.828 us; speedup 1.0000x reference)
//
#include <hip/hip_runtime.h>
#include <math.h>

#define NP 196   // patches per image
#define NC 10    // classes

// Persistent-ish: 512 blocks x 4 waves; each block loops over 4 image-groups
// (4 images per group, split-K over patches as in round 4/5).
// KEY: W[c, 4p..4p+3] depends only on (wave,lane) -> load the 10 float4s of W
// into REGISTERS once per block and reuse across all groups (no per-group W
// traffic). Trig setup also amortizes. Reduce chain unchanged (verified).

template<int CTRL>
__device__ __forceinline__ float dpp_mov(float v) {
    return __int_as_float(__builtin_amdgcn_update_dpp(
        0, __float_as_int(v), CTRL, 0xF, 0xF, true));
}

__device__ __forceinline__ float swz_xor16(float v) {
    return __int_as_float(__builtin_amdgcn_ds_swizzle(__float_as_int(v), 0x401F));
}

// ha,hb are half-angles (0.5*pixel + 0.5*theta0)
__device__ __forceinline__ void sim_pair(float ha, float hb,
                                         float ct0, float st0,
                                         float ct1, float st1,
                                         float& z0, float& z1) {
    float sa = __sinf(ha), ca = __cosf(ha);
    float sb = __sinf(hb), cb = __cosf(hb);
    float p0 = ca * cb, p1 = ca * sb, p2 = sa * sb, p3 = sa * cb;
    float q0 = ct0 * p0 - st0 * p2, q2 = st0 * p0 + ct0 * p2;
    float q1 = ct0 * p1 - st0 * p3, q3 = st0 * p1 + ct0 * p3;
    float r0 = ct1 * q0 - st1 * q1, r1 = st1 * q0 + ct1 * q1;
    float r2 = ct1 * q2 - st1 * q3, r3 = st1 * q2 + ct1 * q3;
    float e0 = r0 * r0, e1 = r1 * r1, e2 = r2 * r2, e3 = r3 * r3;
    z0 = (e0 + e1) - (e2 + e3);
    z1 = (e0 - e1) + (e3 - e2);
}

__global__ __launch_bounds__(256, 2) void quanv_fused(
    const float* __restrict__ x,      // (B, 784)
    const float* __restrict__ theta,  // (2, 4)
    const float* __restrict__ W,      // (10, 784)
    const float* __restrict__ bias,   // (10,)
    float* __restrict__ out,          // (B, 10)
    int B)
{
    __shared__ float s_part[4][4][16];   // [wave][row][class]

    const int tid  = threadIdx.x;
    const int lane = tid & 63;
    const int wv   = tid >> 6;

    // uniform setup (once per block)
    const float ht0 = 0.5f * theta[0], ht1 = 0.5f * theta[1];
    const float ht2 = 0.5f * theta[2], ht3 = 0.5f * theta[3];
    float ct[4], st[4];
#pragma unroll
    for (int w = 0; w < 4; ++w) {
        const float h = 0.5f * theta[4 + w];
        st[w] = __sinf(h);
        ct[w] = __cosf(h);
    }

    // per-lane patch assignment (fixed across groups), branch-free
    const int   lc    = (lane < 49) ? lane : 48;
    const int   p     = wv * 49 + lc;
    const float scale = (lane < 49) ? 1.f : 0.f;
    const int   pi    = p / 14;
    const int   pj    = p - pi * 14;
    const int   off   = pi * 56 + pj * 2;

    // register-cache W for this lane's patch (image-independent!)
    float4 wreg[NC];
#pragma unroll
    for (int c = 0; c < NC; ++c)
        wreg[c] = *(const float4*)(W + c * 784 + p * 4);

    const bool lo32 = (lane & 32) == 0;
    const bool lo16 = (lane & 16) == 0;
    const int  r    = lane >> 4;
    const int  cl   = lane & 15;
    const int  cs   = (cl < NC) ? cl : (NC - 1);
    const int  ngrp = (B + 3) / 4;

    for (int g = blockIdx.x; g < ngrp; g += gridDim.x) {
        const int imgbase = g * 4;
        const float* x0 = x + (size_t)imgbase * 784;

        float f[4][4];
#pragma unroll
        for (int m = 0; m < 4; ++m) {
            const float* xm = x0 + m * 784 + off;
            const float2 r0 = *(const float2*)(xm);
            const float2 r1 = *(const float2*)(xm + 28);
            sim_pair(fmaf(0.5f, r0.x, ht0), fmaf(0.5f, r0.y, ht1),
                     ct[0], st[0], ct[1], st[1], f[m][0], f[m][1]);
            sim_pair(fmaf(0.5f, r1.x, ht2), fmaf(0.5f, r1.y, ht3),
                     ct[2], st[2], ct[3], st[3], f[m][2], f[m][3]);
#pragma unroll
            for (int j = 0; j < 4; ++j) f[m][j] *= scale;
        }

        float acc[4][NC];
#pragma unroll
        for (int c = 0; c < NC; ++c) {
            const float4 w4 = wreg[c];
#pragma unroll
            for (int m = 0; m < 4; ++m) {
                acc[m][c] = fmaf(f[m][0], w4.x, fmaf(f[m][1], w4.y,
                            fmaf(f[m][2], w4.z,      f[m][3] * w4.w)));
            }
        }

        // ---- per-wave reduce (verified chain) ----
        float val = 0.f;
#pragma unroll
        for (int c = 0; c < NC; ++c) {
            float tAB = lo32 ? acc[0][c] : acc[1][c];
            float uAB = lo32 ? acc[1][c] : acc[0][c];
            float mAB = tAB + __shfl_xor(uAB, 32);
            float tCD = lo32 ? acc[2][c] : acc[3][c];
            float uCD = lo32 ? acc[3][c] : acc[2][c];
            float mCD = tCD + __shfl_xor(uCD, 32);
            float t = lo16 ? mAB : mCD;
            float u = lo16 ? mCD : mAB;
            float v = t + swz_xor16(u);
            v = v + dpp_mov<0x124>(v);   // row_ror:4
            v = v + dpp_mov<0x128>(v);   // row_ror:8
            v = v + dpp_mov<0xB1>(v);    // quad_perm xor1
            v = v + dpp_mov<0x4E>(v);    // quad_perm xor2
            val = (cl == c) ? v : val;
        }
        if (cl < NC) s_part[wv][r][cl] = val;
        __syncthreads();

        // ---- wave 0: merge, softmax, store ----
        if (wv == 0) {
            float lsum = s_part[0][r][cs] + s_part[1][r][cs]
                       + s_part[2][r][cs] + s_part[3][r][cs] + bias[cs];
            float logit = (cl < NC) ? lsum : -INFINITY;

            float mx = logit;
            mx = fmaxf(mx, dpp_mov<0x124>(mx));
            mx = fmaxf(mx, dpp_mov<0x128>(mx));
            mx = fmaxf(mx, dpp_mov<0xB1>(mx));
            mx = fmaxf(mx, dpp_mov<0x4E>(mx));

            float e = (cl < NC) ? __expf(logit - mx) : 0.f;
            e = e + dpp_mov<0x124>(e);
            e = e + dpp_mov<0x128>(e);
            e = e + dpp_mov<0xB1>(e);
            e = e + dpp_mov<0x4E>(e);

            const int img = imgbase + ((r & 1) << 1) + (r >> 1);
            if (cl < NC) out[img * NC + cl] = logit - mx - __logf(e);
        }
        __syncthreads();   // protect s_part before next group's writes
    }
}

extern "C" void kernel_launch(void* const* d_in, const int* in_sizes, int n_in,
                              void* d_out, int out_size, void* d_ws, size_t ws_size,
                              hipStream_t stream) {
    const float* x     = (const float*)d_in[0];  // (B,1,28,28)
    const float* theta = (const float*)d_in[1];  // (2,4)
    const float* W     = (const float*)d_in[2];  // (10,784)
    const float* bias  = (const float*)d_in[3];  // (10,)
    float* out = (float*)d_out;                  // (B,10)
    const int B = in_sizes[0] / 784;
    quanv_fused<<<512, 256, 0, stream>>>(x, theta, W, bias, out, B);
}

// Round 7
// 15.682 us; speedup vs baseline: 1.2006x; 1.2006x over previous
//
#include <hip/hip_runtime.h>
#include <math.h>

#define NP 196   // patches per image
#define NC 10    // classes

// One wave = FOUR images (round-3 structure — best measured: 15.59 us).
// Lane l handles patches {l, l+64, l+128} (+192+l for l<4) for all 4 images;
// W float4 loads amortize over 4 images. Logit reduction: xor32 merge,
// xor16 merge, then DPP adds (row_ror:4/8, quad_perm xor1/xor2) on the VALU
// pipe. Softmax per 16-lane row, all in registers.

template<int CTRL>
__device__ __forceinline__ float dpp_add(float v) {
    int t = __builtin_amdgcn_update_dpp(0, __float_as_int(v), CTRL, 0xF, 0xF, true);
    return v + __int_as_float(t);
}

__device__ __forceinline__ float swz_xor16_add(float v) {
    int t = __builtin_amdgcn_ds_swizzle(__float_as_int(v), 0x401F);
    return v + __int_as_float(t);
}

__device__ __forceinline__ void sim_pair(float pxa, float pxb,
                                         float th0a, float th0b,
                                         float ct0, float st0,
                                         float ct1, float st1,
                                         float& z0, float& z1) {
    float sa, ca, sb, cb;
    __sincosf(0.5f * (pxa + th0a), &sa, &ca);
    __sincosf(0.5f * (pxb + th0b), &sb, &cb);
    float p0 = ca * cb, p1 = ca * sb, p2 = sa * sb, p3 = sa * cb;
    float q0 = ct0 * p0 - st0 * p2, q2 = st0 * p0 + ct0 * p2;
    float q1 = ct0 * p1 - st0 * p3, q3 = st0 * p1 + ct0 * p3;
    float r0 = ct1 * q0 - st1 * q1, r1 = st1 * q0 + ct1 * q1;
    float r2 = ct1 * q2 - st1 * q3, r3 = st1 * q2 + ct1 * q3;
    float e0 = r0 * r0, e1 = r1 * r1, e2 = r2 * r2, e3 = r3 * r3;
    z0 = (e0 + e1) - (e2 + e3);
    z1 = (e0 - e1) + (e3 - e2);
}

__global__ __launch_bounds__(256, 2) void quanv_fused(
    const float* __restrict__ x,      // (B, 784)
    const float* __restrict__ theta,  // (2, 4)
    const float* __restrict__ W,      // (10, 784)
    const float* __restrict__ bias,   // (10,)
    float* __restrict__ out,          // (B, 10)
    int B)
{
    const int tid  = threadIdx.x;
    const int lane = tid & 63;
    const int wave = blockIdx.x * 4 + (tid >> 6);
    const int imgbase = wave * 4;
    if (imgbase >= B) return;

    const float th00 = theta[0], th01 = theta[1], th02 = theta[2], th03 = theta[3];
    float ct[4], st[4];
#pragma unroll
    for (int w = 0; w < 4; ++w) __sincosf(0.5f * theta[4 + w], &st[w], &ct[w]);

    const float* x0 = x + (size_t)imgbase * 784;

    float acc[4][NC];
#pragma unroll
    for (int m = 0; m < 4; ++m)
#pragma unroll
        for (int c = 0; c < NC; ++c) acc[m][c] = 0.f;

#pragma unroll
    for (int k = 0; k < 4; ++k) {
        const bool active = (k < 3) || (lane < 4);
        const int p = lane + 64 * k;
        const int pi = p / 14;
        const int pj = p - pi * 14;
        const int off = pi * 56 + pj * 2;

        float f[4][4];
        if (active) {
#pragma unroll
            for (int m = 0; m < 4; ++m) {
                const float* xm = x0 + m * 784 + off;
                const float2 r0 = *(const float2*)(xm);
                const float2 r1 = *(const float2*)(xm + 28);
                sim_pair(r0.x, r0.y, th00, th01, ct[0], st[0], ct[1], st[1],
                         f[m][0], f[m][1]);
                sim_pair(r1.x, r1.y, th02, th03, ct[2], st[2], ct[3], st[3],
                         f[m][2], f[m][3]);
            }
#pragma unroll
            for (int c = 0; c < NC; ++c) {
                const float4 w4 = *(const float4*)(W + c * 784 + p * 4);
#pragma unroll
                for (int m = 0; m < 4; ++m) {
                    acc[m][c] = fmaf(f[m][0], w4.x, fmaf(f[m][1], w4.y,
                                fmaf(f[m][2], w4.z, fmaf(f[m][3], w4.w, acc[m][c]))));
                }
            }
        }
    }

    // ---- reduction ----
    const bool lo32 = (lane & 32) == 0;
    const bool lo16 = (lane & 16) == 0;
    float m4[NC];
#pragma unroll
    for (int c = 0; c < NC; ++c) {
        float tAB = lo32 ? acc[0][c] : acc[1][c];
        float uAB = lo32 ? acc[1][c] : acc[0][c];
        float mAB = tAB + __shfl_xor(uAB, 32);
        float tCD = lo32 ? acc[2][c] : acc[3][c];
        float uCD = lo32 ? acc[3][c] : acc[2][c];
        float mCD = tCD + __shfl_xor(uCD, 32);
        float t = lo16 ? mAB : mCD;
        float u = lo16 ? mCD : mAB;
        float v = t + swz_xor16_add(u) - u;   // t + swizzle16(u)
        v = dpp_add<0x124>(v);   // row_ror:4
        v = dpp_add<0x128>(v);   // row_ror:8
        v = dpp_add<0xB1>(v);    // quad_perm xor1
        v = dpp_add<0x4E>(v);    // quad_perm xor2
        m4[c] = v + bias[c];
    }

    // ---- softmax per 16-lane row ----
    float mx = m4[0];
#pragma unroll
    for (int c = 1; c < NC; ++c) mx = fmaxf(mx, m4[c]);
    float se = 0.f;
#pragma unroll
    for (int c = 0; c < NC; ++c) se += __expf(m4[c] - mx);
    const float lse = mx + __logf(se);

    const int r  = lane >> 4;
    const int cl = lane & 15;
    const int img = imgbase + ((r & 1) << 1) + (r >> 1);
    float val = m4[0];
#pragma unroll
    for (int c = 1; c < NC; ++c) val = (cl == c) ? m4[c] : val;
    if (cl < NC) out[img * NC + cl] = val - lse;
}

extern "C" void kernel_launch(void* const* d_in, const int* in_sizes, int n_in,
                              void* d_out, int out_size, void* d_ws, size_t ws_size,
                              hipStream_t stream) {
    const float* x     = (const float*)d_in[0];  // (B,1,28,28)
    const float* theta = (const float*)d_in[1];  // (2,4)
    const float* W     = (const float*)d_in[2];  // (10,784)
    const float* bias  = (const float*)d_in[3];  // (10,)
    float* out = (float*)d_out;                  // (B,10)
    const int B = in_sizes[0] / 784;
    const int waves  = (B + 3) / 4;              // 4 images per wave
    const int blocks = (waves + 3) / 4;          // 4 waves per block
    quanv_fused<<<blocks, 256, 0, stream>>>(x, theta, W, bias, out, B);
}